// Round 1
// baseline (2364.678 us; speedup 1.0000x reference)
//
#include <hip/hip_runtime.h>
#include <hip/hip_bf16.h>
#include <stdint.h>

// BitNet MLP: x[4096tok,4096] -> (gate,up)[4096,11008] -> relu^2 gate * up
// -> int8 quant -> down[4096,4096].
// All matmuls are exact-integer: int4/int8 activations x ternary weights,
// done with bf16 MFMA (small ints exact in bf16, fp32 accum exact < 2^24).

typedef unsigned short u16;
typedef __bf16 bf16x8 __attribute__((ext_vector_type(8)));
typedef float f32x4 __attribute__((ext_vector_type(4)));

#define HD 4096
#define ID 11008
#define MD 4096          // B*S tokens
#define WN 45088768      // 11008*4096 elements per weight
#define QEPS 1e-5f
#define SQRT7 2.6457513110645907f

#define MFMA16(a, b, c) __builtin_amdgcn_mfma_f32_16x16x32_bf16(a, b, c, 0, 0, 0)

__device__ __forceinline__ u16 f2bf(float f) {
  return (u16)(__float_as_uint(f) >> 16);  // exact for our integer-valued floats
}

// ---------------- absmean reductions (double atomics => deterministic) ------
__global__ __launch_bounds__(256) void abssum_kernel(const float4* __restrict__ w,
                                                     int n4, double* __restrict__ out) {
  float s = 0.f;
  int stride = gridDim.x * blockDim.x;
  for (int i = blockIdx.x * blockDim.x + threadIdx.x; i < n4; i += stride) {
    float4 v = w[i];
    s += fabsf(v.x) + fabsf(v.y) + fabsf(v.z) + fabsf(v.w);
  }
#pragma unroll
  for (int off = 32; off > 0; off >>= 1) s += __shfl_down(s, off);
  __shared__ float red[4];
  int l = threadIdx.x & 63, wv = threadIdx.x >> 6;
  if (l == 0) red[wv] = s;
  __syncthreads();
  if (threadIdx.x == 0) {
    double t = (double)red[0] + (double)red[1] + (double)red[2] + (double)red[3];
    atomicAdd(out, t);
  }
}

// ---------------- per-row beta + int4 quant of x -> bf16 ints ---------------
__global__ __launch_bounds__(256) void quantx_kernel(const float* __restrict__ x,
                                                     u16* __restrict__ xq,
                                                     float* __restrict__ scale_x) {
  int row = blockIdx.x;
  const float4* xr = (const float4*)(x + (size_t)row * HD);
  u16* qr = xq + (size_t)row * HD;
  int t = threadIdx.x;
  float4 v[4];
  float s = 0.f;
#pragma unroll
  for (int k = 0; k < 4; ++k) {
    v[k] = xr[t + k * 256];
    s += fabsf(v[k].x) + fabsf(v[k].y) + fabsf(v[k].z) + fabsf(v[k].w);
  }
#pragma unroll
  for (int off = 32; off > 0; off >>= 1) s += __shfl_down(s, off);
  __shared__ float red[4];
  int l = t & 63, wv = t >> 6;
  if (l == 0) red[wv] = s;
  __syncthreads();
  float beta = (red[0] + red[1] + red[2] + red[3]) * (1.f / (float)HD);
  if (t == 0) scale_x[row] = (beta * SQRT7) / SQRT7;  // match ref's dequant scale
  float inv = SQRT7 / (beta + QEPS);
#pragma unroll
  for (int k = 0; k < 4; ++k) {
    ushort4 o;
    o.x = f2bf(fminf(fmaxf(rintf(v[k].x * inv), -8.f), 7.f));
    o.y = f2bf(fminf(fmaxf(rintf(v[k].y * inv), -8.f), 7.f));
    o.z = f2bf(fminf(fmaxf(rintf(v[k].z * inv), -8.f), 7.f));
    o.w = f2bf(fminf(fmaxf(rintf(v[k].w * inv), -8.f), 7.f));
    ((ushort4*)qr)[t + k * 256] = o;
  }
}

// ---------------- ternary quant of a weight -> bf16 {-1,0,1} ----------------
__global__ __launch_bounds__(256) void quantw_kernel(const float4* __restrict__ w,
                                                     u16* __restrict__ wq,
                                                     const double* __restrict__ sum) {
  float mean = (float)(*sum * (1.0 / (double)WN));
  float inv = 1.f / (mean + QEPS);
  int n4 = WN / 4;
  int stride = gridDim.x * blockDim.x;
  for (int i = blockIdx.x * blockDim.x + threadIdx.x; i < n4; i += stride) {
    float4 v = w[i];
    ushort4 o;
    o.x = f2bf(fminf(fmaxf(rintf(v.x * inv), -1.f), 1.f));
    o.y = f2bf(fminf(fmaxf(rintf(v.y * inv), -1.f), 1.f));
    o.z = f2bf(fminf(fmaxf(rintf(v.z * inv), -1.f), 1.f));
    o.w = f2bf(fminf(fmaxf(rintf(v.w * inv), -1.f), 1.f));
    ((ushort4*)wq)[i] = o;
  }
}

// ------------- global->LDS async stage of a 128x64 bf16 tile ----------------
// LDS dest must be wave-uniform; lane l auto-lands at base + l*16B.
__device__ __forceinline__ void stage128x64(const u16* __restrict__ g, int ld,
                                            u16* lds, int w, int l) {
  const u16* gp = g + (size_t)(w * 8 + (l >> 3)) * ld + (l & 7) * 8;
  u16* lp = lds + w * 8 * 64;
#pragma unroll
  for (int i = 0; i < 4; ++i) {
    __builtin_amdgcn_global_load_lds(
        (const __attribute__((address_space(1))) void*)gp,
        (__attribute__((address_space(3))) void*)lp, 16, 0, 0);
    gp += (size_t)32 * ld;
    lp += 32 * 64;
  }
}

// ---------------- GEMM1: dual-B (gate+up), fused relu^2 * up, gamma ---------
__global__ __launch_bounds__(256) void gemm1_kernel(
    const u16* __restrict__ xq, const u16* __restrict__ wgq,
    const u16* __restrict__ wuq, const float* __restrict__ scale_x,
    const double* __restrict__ sums, const float* __restrict__ sg,
    const float* __restrict__ su, float* __restrict__ h,
    unsigned* __restrict__ gbits) {
  __shared__ u16 Al[128 * 64], Bgl[128 * 64], Bul[128 * 64];
  __shared__ unsigned rowmax[128];
  int bid = blockIdx.x;
  int wgid = (bid & 7) * 344 + (bid >> 3);  // XCD swizzle (2752 = 8*344)
  int bm = wgid / 86, bn = wgid % 86;
  int t = threadIdx.x, w = t >> 6, l = t & 63;
  if (t < 128) rowmax[t] = 0u;
  const u16* ga = xq + (size_t)bm * 128 * HD;
  const u16* gb0 = wgq + (size_t)bn * 128 * HD;
  const u16* gb1 = wuq + (size_t)bn * 128 * HD;
  f32x4 accg[4][4] = {};
  f32x4 accu[4][4] = {};
  int wr = (w >> 1) * 64, wc = (w & 1) * 64;
  int lr = l & 15, lk = (l >> 4) * 8;
  for (int k0 = 0; k0 < HD; k0 += 64) {
    stage128x64(ga + k0, HD, Al, w, l);
    stage128x64(gb0 + k0, HD, Bgl, w, l);
    stage128x64(gb1 + k0, HD, Bul, w, l);
    __syncthreads();
#pragma unroll
    for (int ks = 0; ks < 2; ++ks) {
      int ko = ks * 32 + lk;
      bf16x8 a[4];
#pragma unroll
      for (int mi = 0; mi < 4; ++mi)
        a[mi] = *(const bf16x8*)&Al[(wr + mi * 16 + lr) * 64 + ko];
#pragma unroll
      for (int ni = 0; ni < 4; ++ni) {
        bf16x8 b = *(const bf16x8*)&Bgl[(wc + ni * 16 + lr) * 64 + ko];
#pragma unroll
        for (int mi = 0; mi < 4; ++mi) accg[mi][ni] = MFMA16(a[mi], b, accg[mi][ni]);
      }
#pragma unroll
      for (int ni = 0; ni < 4; ++ni) {
        bf16x8 b = *(const bf16x8*)&Bul[(wc + ni * 16 + lr) * 64 + ko];
#pragma unroll
        for (int mi = 0; mi < 4; ++mi) accu[mi][ni] = MFMA16(a[mi], b, accu[mi][ni]);
      }
    }
    __syncthreads();
  }
  float gm = (float)(sums[0] * (1.0 / (double)WN)) * sg[0];
  float um = (float)(sums[1] * (1.0 / (double)WN)) * su[0];
  float pm[4][4];
#pragma unroll
  for (int mi = 0; mi < 4; ++mi)
#pragma unroll
    for (int j = 0; j < 4; ++j) pm[mi][j] = 0.f;
#pragma unroll
  for (int mi = 0; mi < 4; ++mi) {
    int rb = bm * 128 + wr + mi * 16 + (l >> 4) * 4;
    float sxa[4];
#pragma unroll
    for (int j = 0; j < 4; ++j) sxa[j] = scale_x[rb + j];
#pragma unroll
    for (int ni = 0; ni < 4; ++ni) {
      int col = bn * 128 + wc + ni * 16 + lr;
#pragma unroll
      for (int j = 0; j < 4; ++j) {
        float g = accg[mi][ni][j] * (sxa[j] * gm);
        float u = accu[mi][ni][j] * (sxa[j] * um);
        float rg = fmaxf(g, 0.f);
        float hv = u * rg * rg;
        h[(size_t)(rb + j) * ID + col] = hv;
        pm[mi][j] = fmaxf(pm[mi][j], fabsf(hv));
      }
    }
  }
#pragma unroll
  for (int mi = 0; mi < 4; ++mi)
#pragma unroll
    for (int j = 0; j < 4; ++j) {
      float v2 = pm[mi][j];
      v2 = fmaxf(v2, __shfl_xor(v2, 1));
      v2 = fmaxf(v2, __shfl_xor(v2, 2));
      v2 = fmaxf(v2, __shfl_xor(v2, 4));
      v2 = fmaxf(v2, __shfl_xor(v2, 8));
      pm[mi][j] = v2;
    }
  if ((l & 15) == 0) {
#pragma unroll
    for (int mi = 0; mi < 4; ++mi)
#pragma unroll
      for (int j = 0; j < 4; ++j)
        atomicMax(&rowmax[wr + mi * 16 + (l >> 4) * 4 + j], __float_as_uint(pm[mi][j]));
  }
  __syncthreads();
  if (t < 128) atomicMax(&gbits[bm * 128 + t], rowmax[t]);
}

// ---------------- int8 quant of h -> bf16 ints ------------------------------
__global__ __launch_bounds__(256) void quanth_kernel(const float4* __restrict__ h,
                                                     const unsigned* __restrict__ gbits,
                                                     u16* __restrict__ hq) {
  int n4 = WN / 4;  // 11272192, row = i / 2752
  int stride = gridDim.x * blockDim.x;
  for (int i = blockIdx.x * blockDim.x + threadIdx.x; i < n4; i += stride) {
    int row = i / 2752;
    float gam = __uint_as_float(gbits[row]);
    float inv = 127.f / (gam + QEPS);
    float4 v = h[i];
    ushort4 o;
    o.x = f2bf(fminf(fmaxf(rintf(v.x * inv), -128.f), 127.f));
    o.y = f2bf(fminf(fmaxf(rintf(v.y * inv), -128.f), 127.f));
    o.z = f2bf(fminf(fmaxf(rintf(v.z * inv), -128.f), 127.f));
    o.w = f2bf(fminf(fmaxf(rintf(v.w * inv), -128.f), 127.f));
    ((ushort4*)hq)[i] = o;
  }
}

// ---------------- GEMM2: inter x w_down ------------------------------------
__global__ __launch_bounds__(256) void gemm2_kernel(
    const u16* __restrict__ hq, const u16* __restrict__ wdq,
    const unsigned* __restrict__ gbits, const double* __restrict__ sums,
    const float* __restrict__ sd, float* __restrict__ out) {
  __shared__ u16 Al[128 * 64], Bl[128 * 64];
  int bid = blockIdx.x;
  int wgid = (bid & 7) * 128 + (bid >> 3);  // 1024 = 8*128
  int bm = wgid >> 5, bn = wgid & 31;
  int t = threadIdx.x, w = t >> 6, l = t & 63;
  const u16* ga = hq + (size_t)bm * 128 * ID;
  const u16* gb = wdq + (size_t)bn * 128 * ID;
  f32x4 acc[4][4] = {};
  int wr = (w >> 1) * 64, wc = (w & 1) * 64;
  int lr = l & 15, lk = (l >> 4) * 8;
  for (int k0 = 0; k0 < ID; k0 += 64) {
    stage128x64(ga + k0, ID, Al, w, l);
    stage128x64(gb + k0, ID, Bl, w, l);
    __syncthreads();
#pragma unroll
    for (int ks = 0; ks < 2; ++ks) {
      int ko = ks * 32 + lk;
      bf16x8 a[4];
#pragma unroll
      for (int mi = 0; mi < 4; ++mi)
        a[mi] = *(const bf16x8*)&Al[(wr + mi * 16 + lr) * 64 + ko];
#pragma unroll
      for (int ni = 0; ni < 4; ++ni) {
        bf16x8 b = *(const bf16x8*)&Bl[(wc + ni * 16 + lr) * 64 + ko];
#pragma unroll
        for (int mi = 0; mi < 4; ++mi) acc[mi][ni] = MFMA16(a[mi], b, acc[mi][ni]);
      }
    }
    __syncthreads();
  }
  float wdm = (float)(sums[2] * (1.0 / (double)WN)) * sd[0] * (1.f / 127.f);
#pragma unroll
  for (int mi = 0; mi < 4; ++mi) {
    int rb = bm * 128 + wr + mi * 16 + (l >> 4) * 4;
    float sa[4];
#pragma unroll
    for (int j = 0; j < 4; ++j) sa[j] = __uint_as_float(gbits[rb + j]) * wdm;
#pragma unroll
    for (int ni = 0; ni < 4; ++ni) {
      int col = bn * 128 + wc + ni * 16 + lr;
#pragma unroll
      for (int j = 0; j < 4; ++j)
        out[(size_t)(rb + j) * HD + col] = acc[mi][ni][j] * sa[j];
    }
  }
}

extern "C" void kernel_launch(void* const* d_in, const int* in_sizes, int n_in,
                              void* d_out, int out_size, void* d_ws, size_t ws_size,
                              hipStream_t stream) {
  (void)in_sizes; (void)n_in; (void)out_size; (void)ws_size;
  const float* x = (const float*)d_in[0];
  const float* w_gate = (const float*)d_in[1];
  const float* w_up = (const float*)d_in[2];
  const float* w_down = (const float*)d_in[3];
  const float* s_gate = (const float*)d_in[4];
  const float* s_up = (const float*)d_in[5];
  const float* s_down = (const float*)d_in[6];
  float* out = (float*)d_out;

  // ws layout (bytes):
  char* p = (char*)d_ws;
  double* sums = (double*)p;                         // 3 doubles
  unsigned* gbits = (unsigned*)(p + 256);            // 4096 u32
  float* scale_x = (float*)(p + 256 + 16384);        // 4096 f32 -> end 33024
  u16* xq = (u16*)(p + 33024);                       // 33,554,432 B
  u16* wgq = (u16*)(p + 33024 + 33554432UL);         // 90,177,536 B each
  u16* wuq = wgq + (size_t)WN;
  u16* wdq = wuq + (size_t)WN;
  float* h = (float*)(p + 33024 + 33554432UL + 3UL * 90177536UL);  // 180,355,072 B
  u16* hq = (u16*)((char*)h + 180355072UL);          // 90,177,536 B  (total ~575 MB)

  hipMemsetAsync(p, 0, 33024, stream);  // sums + gamma bits

  abssum_kernel<<<2048, 256, 0, stream>>>((const float4*)w_gate, WN / 4, sums + 0);
  abssum_kernel<<<2048, 256, 0, stream>>>((const float4*)w_up, WN / 4, sums + 1);
  abssum_kernel<<<2048, 256, 0, stream>>>((const float4*)w_down, WN / 4, sums + 2);

  quantx_kernel<<<MD, 256, 0, stream>>>(x, xq, scale_x);
  quantw_kernel<<<2048, 256, 0, stream>>>((const float4*)w_gate, wgq, sums + 0);
  quantw_kernel<<<2048, 256, 0, stream>>>((const float4*)w_up, wuq, sums + 1);
  quantw_kernel<<<2048, 256, 0, stream>>>((const float4*)w_down, wdq, sums + 2);

  gemm1_kernel<<<2752, 256, 0, stream>>>(xq, wgq, wuq, scale_x, sums, s_gate, s_up, h, gbits);
  quanth_kernel<<<2048, 256, 0, stream>>>((const float4*)h, gbits, hq);
  gemm2_kernel<<<1024, 256, 0, stream>>>(hq, wdq, gbits, sums, s_down, out);
}

// Round 3
// 1276.867 us; speedup vs baseline: 1.8519x; 1.8519x over previous
//
#include <hip/hip_runtime.h>
#include <hip/hip_bf16.h>
#include <stdint.h>

// BitNet MLP, int8-MFMA formulation.
// x[4096,4096] --int4 quant--> xq(i8) ; weights --ternary quant--> {-1,0,1}(i8)
// gate/up = i8 GEMM (exact int32), epilogue: fp32 scales, relu^2*up -> h(f32)
// + per-row absmax gamma ; h --int8 quant--> hq(i8) ; out = i8 GEMM * scales.
// All integer dot products are exact; only the fp32 scale factors round.

typedef int i32x4 __attribute__((ext_vector_type(4)));

#define HD 4096
#define ID 11008
#define MD 4096          // B*S tokens
#define WN 45088768      // 11008*4096 elements per weight
#define QEPS 1e-5f
#define SQRT7 2.6457513110645907f

#define MFMA_I8(a, b, c) __builtin_amdgcn_mfma_i32_16x16x64_i8(a, b, c, 0, 0, 0)

__device__ __forceinline__ int pack4(float4 v, float inv, float lo, float hi) {
  int a = (int)fminf(fmaxf(rintf(v.x * inv), lo), hi);
  int b = (int)fminf(fmaxf(rintf(v.y * inv), lo), hi);
  int c = (int)fminf(fmaxf(rintf(v.z * inv), lo), hi);
  int d = (int)fminf(fmaxf(rintf(v.w * inv), lo), hi);
  return (a & 255) | ((b & 255) << 8) | ((c & 255) << 16) | ((d & 255) << 24);
}

// ---------------- absmean reductions (double atomics) -----------------------
__global__ __launch_bounds__(256) void abssum_kernel(const float4* __restrict__ w,
                                                     int n4, double* __restrict__ out) {
  float s = 0.f;
  int stride = gridDim.x * blockDim.x;
  for (int i = blockIdx.x * blockDim.x + threadIdx.x; i < n4; i += stride) {
    float4 v = w[i];
    s += fabsf(v.x) + fabsf(v.y) + fabsf(v.z) + fabsf(v.w);
  }
#pragma unroll
  for (int off = 32; off > 0; off >>= 1) s += __shfl_down(s, off);
  __shared__ float red[4];
  int l = threadIdx.x & 63, wv = threadIdx.x >> 6;
  if (l == 0) red[wv] = s;
  __syncthreads();
  if (threadIdx.x == 0) {
    double t = (double)red[0] + (double)red[1] + (double)red[2] + (double)red[3];
    atomicAdd(out, t);
  }
}

// ---------------- per-row beta + int4 quant of x -> i8 ----------------------
__global__ __launch_bounds__(256) void quantx_kernel(const float* __restrict__ x,
                                                     char* __restrict__ xq,
                                                     float* __restrict__ scale_x) {
  int row = blockIdx.x;
  const float4* xr = (const float4*)(x + (size_t)row * HD);
  int t = threadIdx.x;
  float4 v[4];
  float s = 0.f;
#pragma unroll
  for (int k = 0; k < 4; ++k) {
    v[k] = xr[t * 4 + k];
    s += fabsf(v[k].x) + fabsf(v[k].y) + fabsf(v[k].z) + fabsf(v[k].w);
  }
#pragma unroll
  for (int off = 32; off > 0; off >>= 1) s += __shfl_down(s, off);
  __shared__ float red[4];
  int l = t & 63, wv = t >> 6;
  if (l == 0) red[wv] = s;
  __syncthreads();
  float beta = (red[0] + red[1] + red[2] + red[3]) * (1.f / (float)HD);
  if (t == 0) scale_x[row] = (beta * SQRT7) / SQRT7;  // match ref's dequant scale
  float inv = SQRT7 / (beta + QEPS);
  int4 o;
  o.x = pack4(v[0], inv, -8.f, 7.f);
  o.y = pack4(v[1], inv, -8.f, 7.f);
  o.z = pack4(v[2], inv, -8.f, 7.f);
  o.w = pack4(v[3], inv, -8.f, 7.f);
  ((int4*)(xq + (size_t)row * HD))[t] = o;
}

// ---------------- ternary quant of a weight -> i8 {-1,0,1} ------------------
__global__ __launch_bounds__(256) void quantw_kernel(const float4* __restrict__ w,
                                                     int4* __restrict__ wq,
                                                     const double* __restrict__ sum) {
  float mean = (float)(*sum * (1.0 / (double)WN));
  float inv = 1.f / (mean + QEPS);
  int n16 = WN / 16;
  int stride = gridDim.x * blockDim.x;
  for (int i = blockIdx.x * blockDim.x + threadIdx.x; i < n16; i += stride) {
    float4 v0 = w[i * 4 + 0], v1 = w[i * 4 + 1], v2 = w[i * 4 + 2], v3 = w[i * 4 + 3];
    int4 o;
    o.x = pack4(v0, inv, -1.f, 1.f);
    o.y = pack4(v1, inv, -1.f, 1.f);
    o.z = pack4(v2, inv, -1.f, 1.f);
    o.w = pack4(v3, inv, -1.f, 1.f);
    wq[i] = o;
  }
}

// ------------- global->LDS stage of a 128x128 i8 tile, pre-swizzled source --
// LDS dest is linear (lane l lands at base + l*16). We want the LDS image
// swizzled as byte ^= ((row&7)<<4), so the SOURCE column is inverse-swizzled:
// lane l (writing row ..+(l>>3), slot l&7) reads global slot (l&7)^(l>>3).
__device__ __forceinline__ void stage_i8(const char* __restrict__ g, int ld,
                                         char* lds, int w, int l) {
  const char* gp = g + (size_t)(w * 32 + (l >> 3)) * ld + ((l & 7) ^ (l >> 3)) * 16;
  char* lp = lds + w * 4096;
#pragma unroll
  for (int i = 0; i < 4; ++i) {
    __builtin_amdgcn_global_load_lds(
        (const __attribute__((address_space(1))) void*)gp,
        (__attribute__((address_space(3))) void*)lp, 16, 0, 0);
    gp += (size_t)8 * ld;
    lp += 1024;
  }
}

// ---------------- GEMM1: dual-B (gate+up), fused relu^2 * up, gamma ---------
__global__ __launch_bounds__(256) void gemm1_kernel(
    const char* __restrict__ xq, const char* __restrict__ wgq,
    const char* __restrict__ wuq, const float* __restrict__ scale_x,
    const double* __restrict__ sums, const float* __restrict__ sg,
    const float* __restrict__ su, float* __restrict__ h,
    unsigned* __restrict__ gbits) {
  __shared__ __align__(16) char Al[128 * 128], Bgl[128 * 128], Bul[128 * 128];
  __shared__ unsigned rowmax[128];
  int bid = blockIdx.x;
  int wgid = (bid & 7) * 344 + (bid >> 3);  // XCD swizzle (2752 = 8*344)
  int bm = wgid / 86, bn = wgid % 86;
  int t = threadIdx.x, w = t >> 6, l = t & 63;
  if (t < 128) rowmax[t] = 0u;
  const char* ga = xq + (size_t)bm * 128 * HD;
  const char* gb0 = wgq + (size_t)bn * 128 * HD;
  const char* gb1 = wuq + (size_t)bn * 128 * HD;
  i32x4 accg[4][4] = {};
  i32x4 accu[4][4] = {};
  int wr = (w >> 1) * 64, wc = (w & 1) * 64;
  int lr = l & 15;
  int sw = (l & 7) << 4;  // (row&7)<<4 for all this lane's fragment rows
  for (int k0 = 0; k0 < HD; k0 += 128) {
    stage_i8(ga + k0, HD, Al, w, l);
    stage_i8(gb0 + k0, HD, Bgl, w, l);
    stage_i8(gb1 + k0, HD, Bul, w, l);
    __syncthreads();
#pragma unroll
    for (int ks = 0; ks < 2; ++ks) {
      int kx = (ks * 64 + (l >> 4) * 16) ^ sw;
      i32x4 a[4];
#pragma unroll
      for (int mi = 0; mi < 4; ++mi)
        a[mi] = *(const i32x4*)&Al[(wr + mi * 16 + lr) * 128 + kx];
#pragma unroll
      for (int ni = 0; ni < 4; ++ni) {
        i32x4 b = *(const i32x4*)&Bgl[(wc + ni * 16 + lr) * 128 + kx];
#pragma unroll
        for (int mi = 0; mi < 4; ++mi) accg[mi][ni] = MFMA_I8(a[mi], b, accg[mi][ni]);
      }
#pragma unroll
      for (int ni = 0; ni < 4; ++ni) {
        i32x4 b = *(const i32x4*)&Bul[(wc + ni * 16 + lr) * 128 + kx];
#pragma unroll
        for (int mi = 0; mi < 4; ++mi) accu[mi][ni] = MFMA_I8(a[mi], b, accu[mi][ni]);
      }
    }
    __syncthreads();
  }
  float gm = (float)(sums[0] * (1.0 / (double)WN)) * sg[0];
  float um = (float)(sums[1] * (1.0 / (double)WN)) * su[0];
  float pm[4][4];
#pragma unroll
  for (int mi = 0; mi < 4; ++mi)
#pragma unroll
    for (int j = 0; j < 4; ++j) pm[mi][j] = 0.f;
#pragma unroll
  for (int mi = 0; mi < 4; ++mi) {
    int rb = bm * 128 + wr + mi * 16 + (l >> 4) * 4;
    float sxa[4];
#pragma unroll
    for (int j = 0; j < 4; ++j) sxa[j] = scale_x[rb + j];
#pragma unroll
    for (int ni = 0; ni < 4; ++ni) {
      int col = bn * 128 + wc + ni * 16 + lr;
#pragma unroll
      for (int j = 0; j < 4; ++j) {
        float g = (float)accg[mi][ni][j] * (sxa[j] * gm);
        float u = (float)accu[mi][ni][j] * (sxa[j] * um);
        float rg = fmaxf(g, 0.f);
        float hv = u * rg * rg;
        h[(size_t)(rb + j) * ID + col] = hv;
        pm[mi][j] = fmaxf(pm[mi][j], fabsf(hv));
      }
    }
  }
#pragma unroll
  for (int mi = 0; mi < 4; ++mi)
#pragma unroll
    for (int j = 0; j < 4; ++j) {
      float v2 = pm[mi][j];
      v2 = fmaxf(v2, __shfl_xor(v2, 1));
      v2 = fmaxf(v2, __shfl_xor(v2, 2));
      v2 = fmaxf(v2, __shfl_xor(v2, 4));
      v2 = fmaxf(v2, __shfl_xor(v2, 8));
      pm[mi][j] = v2;
    }
  if ((l & 15) == 0) {
#pragma unroll
    for (int mi = 0; mi < 4; ++mi)
#pragma unroll
      for (int j = 0; j < 4; ++j)
        atomicMax(&rowmax[wr + mi * 16 + (l >> 4) * 4 + j], __float_as_uint(pm[mi][j]));
  }
  __syncthreads();
  if (t < 128) atomicMax(&gbits[bm * 128 + t], rowmax[t]);
}

// ---------------- int8 quant of h -> i8 -------------------------------------
__global__ __launch_bounds__(256) void quanth_kernel(const float4* __restrict__ h,
                                                     const unsigned* __restrict__ gbits,
                                                     int4* __restrict__ hq) {
  int n16 = WN / 16;  // row = i / 688 (11008/16)
  int stride = gridDim.x * blockDim.x;
  for (int i = blockIdx.x * blockDim.x + threadIdx.x; i < n16; i += stride) {
    int row = i / 688;
    float gam = __uint_as_float(gbits[row]);
    float inv = 127.f / (gam + QEPS);
    float4 v0 = h[i * 4 + 0], v1 = h[i * 4 + 1], v2 = h[i * 4 + 2], v3 = h[i * 4 + 3];
    int4 o;
    o.x = pack4(v0, inv, -128.f, 127.f);
    o.y = pack4(v1, inv, -128.f, 127.f);
    o.z = pack4(v2, inv, -128.f, 127.f);
    o.w = pack4(v3, inv, -128.f, 127.f);
    hq[i] = o;
  }
}

// ---------------- GEMM2: inter x w_down ------------------------------------
__global__ __launch_bounds__(256) void gemm2_kernel(
    const char* __restrict__ hq, const char* __restrict__ wdq,
    const unsigned* __restrict__ gbits, const double* __restrict__ sums,
    const float* __restrict__ sd, float* __restrict__ out) {
  __shared__ __align__(16) char Al[128 * 128], Bl[128 * 128];
  int bid = blockIdx.x;
  int wgid = (bid & 7) * 128 + (bid >> 3);  // 1024 = 8*128
  int bm = wgid >> 5, bn = wgid & 31;
  int t = threadIdx.x, w = t >> 6, l = t & 63;
  const char* ga = hq + (size_t)bm * 128 * ID;
  const char* gb = wdq + (size_t)bn * 128 * ID;
  i32x4 acc[4][4] = {};
  int wr = (w >> 1) * 64, wc = (w & 1) * 64;
  int lr = l & 15;
  int sw = (l & 7) << 4;
  for (int k0 = 0; k0 < ID; k0 += 128) {
    stage_i8(ga + k0, ID, Al, w, l);
    stage_i8(gb + k0, ID, Bl, w, l);
    __syncthreads();
#pragma unroll
    for (int ks = 0; ks < 2; ++ks) {
      int kx = (ks * 64 + (l >> 4) * 16) ^ sw;
      i32x4 a[4];
#pragma unroll
      for (int mi = 0; mi < 4; ++mi)
        a[mi] = *(const i32x4*)&Al[(wr + mi * 16 + lr) * 128 + kx];
#pragma unroll
      for (int ni = 0; ni < 4; ++ni) {
        i32x4 b = *(const i32x4*)&Bl[(wc + ni * 16 + lr) * 128 + kx];
#pragma unroll
        for (int mi = 0; mi < 4; ++mi) acc[mi][ni] = MFMA_I8(a[mi], b, acc[mi][ni]);
      }
    }
    __syncthreads();
  }
  float wdm = (float)(sums[2] * (1.0 / (double)WN)) * sd[0] * (1.f / 127.f);
#pragma unroll
  for (int mi = 0; mi < 4; ++mi) {
    int rb = bm * 128 + wr + mi * 16 + (l >> 4) * 4;
    float sa[4];
#pragma unroll
    for (int j = 0; j < 4; ++j) sa[j] = __uint_as_float(gbits[rb + j]) * wdm;
#pragma unroll
    for (int ni = 0; ni < 4; ++ni) {
      int col = bn * 128 + wc + ni * 16 + lr;
#pragma unroll
      for (int j = 0; j < 4; ++j)
        out[(size_t)(rb + j) * HD + col] = (float)acc[mi][ni][j] * sa[j];
    }
  }
}

extern "C" void kernel_launch(void* const* d_in, const int* in_sizes, int n_in,
                              void* d_out, int out_size, void* d_ws, size_t ws_size,
                              hipStream_t stream) {
  (void)in_sizes; (void)n_in; (void)out_size; (void)ws_size;
  const float* x = (const float*)d_in[0];
  const float* w_gate = (const float*)d_in[1];
  const float* w_up = (const float*)d_in[2];
  const float* w_down = (const float*)d_in[3];
  const float* s_gate = (const float*)d_in[4];
  const float* s_up = (const float*)d_in[5];
  const float* s_down = (const float*)d_in[6];
  float* out = (float*)d_out;

  // ws layout (bytes):
  char* p = (char*)d_ws;
  double* sums = (double*)p;                       // 3 doubles
  unsigned* gbits = (unsigned*)(p + 256);          // 4096 u32
  float* scale_x = (float*)(p + 256 + 16384);      // 4096 f32 -> head ends 33024
  char* xq = p + 33024;                            // 16,777,216 B
  char* wgq = xq + 16777216UL;                     // 45,088,768 B each
  char* wuq = wgq + (size_t)WN;
  char* wdq = wuq + (size_t)WN;
  float* h = (float*)(wdq + (size_t)WN);           // 180,355,072 B
  char* hq = (char*)h + 180355072UL;               // 45,088,768 B  (~378 MB total)

  (void)hipMemsetAsync(p, 0, 33024, stream);  // sums + gamma bits

  abssum_kernel<<<2048, 256, 0, stream>>>((const float4*)w_gate, WN / 4, sums + 0);
  abssum_kernel<<<2048, 256, 0, stream>>>((const float4*)w_up, WN / 4, sums + 1);
  abssum_kernel<<<2048, 256, 0, stream>>>((const float4*)w_down, WN / 4, sums + 2);

  quantx_kernel<<<MD, 256, 0, stream>>>(x, xq, scale_x);
  quantw_kernel<<<2048, 256, 0, stream>>>((const float4*)w_gate, (int4*)wgq, sums + 0);
  quantw_kernel<<<2048, 256, 0, stream>>>((const float4*)w_up, (int4*)wuq, sums + 1);
  quantw_kernel<<<2048, 256, 0, stream>>>((const float4*)w_down, (int4*)wdq, sums + 2);

  gemm1_kernel<<<2752, 256, 0, stream>>>(xq, wgq, wuq, scale_x, sums, s_gate, s_up, h, gbits);
  quanth_kernel<<<2048, 256, 0, stream>>>((const float4*)h, gbits, (int4*)hq);
  gemm2_kernel<<<1024, 256, 0, stream>>>(hq, wdq, gbits, sums, s_down, out);
}

// Round 4
// 1148.643 us; speedup vs baseline: 2.0587x; 1.1116x over previous
//
#include <hip/hip_runtime.h>
#include <stdint.h>

// BitNet MLP, int8-MFMA, 256^2 deep-pipelined GEMM template.
// gate/up = i8 GEMM -> raw i32 ; combine: relu^2*up, per-row gamma, int8 quant
// (h stays in registers) ; down = i8 GEMM with fused scales.
// All integer dot products exact; only fp32 scale factors round.

typedef int i32x4 __attribute__((ext_vector_type(4)));

#define HD 4096
#define ID 11008
#define MD 4096          // B*S tokens
#define WN 45088768      // 11008*4096 per weight
#define QEPS 1e-5f
#define SQRT7 2.6457513110645907f

#define MFMA_I8(a, b, c) __builtin_amdgcn_mfma_i32_16x16x64_i8(a, b, c, 0, 0, 0)
#define RAWBAR() __builtin_amdgcn_s_barrier()

__device__ __forceinline__ void gload_lds16(const char* g, char* l) {
  __builtin_amdgcn_global_load_lds((const __attribute__((address_space(1))) void*)g,
                                   (__attribute__((address_space(3))) void*)l, 16, 0, 0);
}

// ---- stage a 256row x 128B K-tile (32KB) with 512 threads, swizzled image ----
// LDS dest linear (lane lands base+l*16); image swizzle: 16B-slot ^= row&7.
// Source column is inverse-swizzled (involution), verified 0 bank conflicts (r3).
__device__ __forceinline__ void stage256(const char* __restrict__ g, int ldk,
                                         char* lds, int w, int l) {
  const char* gp = g + (size_t)(w * 32 + (l >> 3)) * ldk + (((l & 7) ^ (l >> 3)) << 4);
  char* lp = lds + w * 4096;
#pragma unroll
  for (int i = 0; i < 4; ++i) {
    gload_lds16(gp, lp);
    gp += (size_t)8 * ldk;
    lp += 1024;
  }
}

// ---- 256x256 x K core: 2-deep LDS dbuf, raw barriers, one vmcnt(0)/tile ----
__device__ __forceinline__ void gemm_core(const char* __restrict__ ga,
                                          const char* __restrict__ gb,
                                          int ldk, int nt, char* Al, char* Bl,
                                          i32x4 (&acc)[8][4], int w, int l) {
  const int wr = (w >> 2) * 128, wc = (w & 3) * 64;
  const int lr = l & 15, khi = (l >> 4) * 16, swz = (l & 7) << 4;
  stage256(ga, ldk, Al, w, l);
  stage256(gb, ldk, Bl, w, l);
  asm volatile("s_waitcnt vmcnt(0)" ::: "memory");
  RAWBAR();
  int cur = 0;
  for (int t = 0; t < nt; ++t) {
    const char* Ab = Al + cur * 32768;
    const char* Bb = Bl + cur * 32768;
    if (t + 1 < nt) {  // prefetch next K-tile into the other buffer (disjoint)
      stage256(ga + (size_t)(t + 1) * 128, ldk, Al + (cur ^ 1) * 32768, w, l);
      stage256(gb + (size_t)(t + 1) * 128, ldk, Bl + (cur ^ 1) * 32768, w, l);
    }
    i32x4 af[4][2], b0[2][2], b1[2][2];
    // ---- phase 0: A half0 + B pair0 -> acc[0..3][0..1]
#pragma unroll
    for (int mi = 0; mi < 4; ++mi)
#pragma unroll
      for (int kk = 0; kk < 2; ++kk)
        af[mi][kk] = *(const i32x4*)(Ab + (wr + mi * 16 + lr) * 128 + ((kk * 64 + khi) ^ swz));
#pragma unroll
    for (int n = 0; n < 2; ++n)
#pragma unroll
      for (int kk = 0; kk < 2; ++kk)
        b0[n][kk] = *(const i32x4*)(Bb + (wc + n * 16 + lr) * 128 + ((kk * 64 + khi) ^ swz));
    RAWBAR();
    __builtin_amdgcn_s_setprio(1);
#pragma unroll
    for (int kk = 0; kk < 2; ++kk)
#pragma unroll
      for (int n = 0; n < 2; ++n)
#pragma unroll
        for (int mi = 0; mi < 4; ++mi)
          acc[mi][n] = MFMA_I8(af[mi][kk], b0[n][kk], acc[mi][n]);
    __builtin_amdgcn_s_setprio(0);
    RAWBAR();
    // ---- phase 1: B pair1 -> acc[0..3][2..3]
#pragma unroll
    for (int n = 0; n < 2; ++n)
#pragma unroll
      for (int kk = 0; kk < 2; ++kk)
        b1[n][kk] = *(const i32x4*)(Bb + (wc + 32 + n * 16 + lr) * 128 + ((kk * 64 + khi) ^ swz));
    RAWBAR();
    __builtin_amdgcn_s_setprio(1);
#pragma unroll
    for (int kk = 0; kk < 2; ++kk)
#pragma unroll
      for (int n = 0; n < 2; ++n)
#pragma unroll
        for (int mi = 0; mi < 4; ++mi)
          acc[mi][2 + n] = MFMA_I8(af[mi][kk], b1[n][kk], acc[mi][2 + n]);
    __builtin_amdgcn_s_setprio(0);
    RAWBAR();
    // ---- phase 2: A half1 -> acc[4..7][0..1]
#pragma unroll
    for (int mi = 0; mi < 4; ++mi)
#pragma unroll
      for (int kk = 0; kk < 2; ++kk)
        af[mi][kk] = *(const i32x4*)(Ab + (wr + 64 + mi * 16 + lr) * 128 + ((kk * 64 + khi) ^ swz));
    RAWBAR();
    __builtin_amdgcn_s_setprio(1);
#pragma unroll
    for (int kk = 0; kk < 2; ++kk)
#pragma unroll
      for (int n = 0; n < 2; ++n)
#pragma unroll
        for (int mi = 0; mi < 4; ++mi)
          acc[4 + mi][n] = MFMA_I8(af[mi][kk], b0[n][kk], acc[4 + mi][n]);
    __builtin_amdgcn_s_setprio(0);
    RAWBAR();
    // ---- phase 3: -> acc[4..7][2..3]
    __builtin_amdgcn_s_setprio(1);
#pragma unroll
    for (int kk = 0; kk < 2; ++kk)
#pragma unroll
      for (int n = 0; n < 2; ++n)
#pragma unroll
        for (int mi = 0; mi < 4; ++mi)
          acc[4 + mi][2 + n] = MFMA_I8(af[mi][kk], b1[n][kk], acc[4 + mi][2 + n]);
    __builtin_amdgcn_s_setprio(0);
    // ---- tile end: prefetch landed (had 4 phases), all waves done reading
    asm volatile("s_waitcnt vmcnt(0)" ::: "memory");
    RAWBAR();
    cur ^= 1;
  }
}

// ---------------- GEMM -> raw i32 (gate / up) -------------------------------
__global__ __launch_bounds__(512, 2) void gemm_raw_kernel(
    const char* __restrict__ A, const char* __restrict__ B, int* __restrict__ C,
    int ldk, int nt, int nbn, int ncols) {
  __shared__ __align__(16) char Al[65536], Bl[65536];
  int t = threadIdx.x, w = t >> 6, l = t & 63;
  int q = (int)gridDim.x >> 3;
  int wgid = ((int)blockIdx.x & 7) * q + ((int)blockIdx.x >> 3);  // XCD swizzle
  int bm = wgid / nbn, bn = wgid % nbn;
  i32x4 acc[8][4] = {};
  gemm_core(A + (size_t)bm * 256 * ldk, B + (size_t)bn * 256 * ldk, ldk, nt, Al, Bl, acc, w, l);
  int wr = (w >> 2) * 128, wc = (w & 3) * 64, lr = l & 15, lj = (l >> 4) * 4;
#pragma unroll
  for (int mi = 0; mi < 8; ++mi) {
    int row = bm * 256 + wr + mi * 16 + lj;
#pragma unroll
    for (int ni = 0; ni < 4; ++ni) {
      int col = bn * 256 + wc + ni * 16 + lr;
#pragma unroll
      for (int j = 0; j < 4; ++j)
        C[(size_t)(row + j) * ncols + col] = acc[mi][ni][j];
    }
  }
}

// ---------------- GEMM2: inter x w_down, fused scales -----------------------
__global__ __launch_bounds__(512, 2) void gemm_down_kernel(
    const char* __restrict__ A, const char* __restrict__ B, float* __restrict__ out,
    const float* __restrict__ gammaF, const double* __restrict__ sums,
    const float* __restrict__ sd) {
  __shared__ __align__(16) char Al[65536], Bl[65536];
  int t = threadIdx.x, w = t >> 6, l = t & 63;
  int q = (int)gridDim.x >> 3;
  int wgid = ((int)blockIdx.x & 7) * q + ((int)blockIdx.x >> 3);
  int bm = wgid >> 4, bn = wgid & 15;
  i32x4 acc[8][4] = {};
  gemm_core(A + (size_t)bm * 256 * ID, B + (size_t)bn * 256 * ID, ID, ID / 128, Al, Bl, acc, w, l);
  float wdm = (float)(sums[2] * (1.0 / (double)WN)) * sd[0] * (1.f / 127.f);
  int wr = (w >> 2) * 128, wc = (w & 3) * 64, lr = l & 15, lj = (l >> 4) * 4;
#pragma unroll
  for (int mi = 0; mi < 8; ++mi) {
    int row = bm * 256 + wr + mi * 16 + lj;
    float sa[4];
#pragma unroll
    for (int j = 0; j < 4; ++j) sa[j] = gammaF[row + j] * wdm;
#pragma unroll
    for (int ni = 0; ni < 4; ++ni) {
      int col = bn * 256 + wc + ni * 16 + lr;
#pragma unroll
      for (int j = 0; j < 4; ++j)
        out[(size_t)(row + j) * HD + col] = (float)acc[mi][ni][j] * sa[j];
    }
  }
}

// ---------------- helpers ----------------------------------------------------
__device__ __forceinline__ int pack4div(float4 v, float mul, float den, float lo, float hi) {
  int a = (int)fminf(fmaxf(rintf((v.x * mul) / den), lo), hi);
  int b = (int)fminf(fmaxf(rintf((v.y * mul) / den), lo), hi);
  int c = (int)fminf(fmaxf(rintf((v.z * mul) / den), lo), hi);
  int d = (int)fminf(fmaxf(rintf((v.w * mul) / den), lo), hi);
  return (a & 255) | ((b & 255) << 8) | ((c & 255) << 16) | ((d & 255) << 24);
}

// ---------------- absmean reductions (double atomics) -----------------------
__global__ __launch_bounds__(256) void abssum_kernel(const float4* __restrict__ w,
                                                     int n4, double* __restrict__ out) {
  float s = 0.f;
  int stride = gridDim.x * blockDim.x;
  for (int i = blockIdx.x * blockDim.x + threadIdx.x; i < n4; i += stride) {
    float4 v = w[i];
    s += fabsf(v.x) + fabsf(v.y) + fabsf(v.z) + fabsf(v.w);
  }
#pragma unroll
  for (int off = 32; off > 0; off >>= 1) s += __shfl_down(s, off);
  __shared__ float red[4];
  int l = threadIdx.x & 63, wv = threadIdx.x >> 6;
  if (l == 0) red[wv] = s;
  __syncthreads();
  if (threadIdx.x == 0) {
    double tt = (double)red[0] + (double)red[1] + (double)red[2] + (double)red[3];
    atomicAdd(out, tt);
  }
}

// ---------------- per-row beta + int4 quant of x -> i8 ----------------------
__global__ __launch_bounds__(256) void quantx_kernel(const float* __restrict__ x,
                                                     char* __restrict__ xq,
                                                     float* __restrict__ scale_x) {
  int row = blockIdx.x;
  const float4* xr = (const float4*)(x + (size_t)row * HD);
  int t = threadIdx.x;
  float4 v[4];
  float s = 0.f;
#pragma unroll
  for (int k = 0; k < 4; ++k) {
    v[k] = xr[t + k * 256];
    s += fabsf(v[k].x) + fabsf(v[k].y) + fabsf(v[k].z) + fabsf(v[k].w);
  }
#pragma unroll
  for (int off = 32; off > 0; off >>= 1) s += __shfl_down(s, off);
  __shared__ float red[4];
  int l = t & 63, wv = t >> 6;
  if (l == 0) red[wv] = s;
  __syncthreads();
  float beta = (red[0] + red[1] + red[2] + red[3]) * (1.f / (float)HD);
  if (t == 0) scale_x[row] = (beta * SQRT7) / SQRT7;  // ref dequant scale
  float den = beta + QEPS;
  int* qr = (int*)(xq + (size_t)row * HD);
#pragma unroll
  for (int k = 0; k < 4; ++k)
    qr[t + k * 256] = pack4div(v[k], SQRT7, den, -8.f, 7.f);
}

// ---------------- ternary quant of a weight -> i8 {-1,0,1} ------------------
__global__ __launch_bounds__(256) void quantw_kernel(const float4* __restrict__ w,
                                                     int4* __restrict__ wq,
                                                     const double* __restrict__ sum) {
  float mean = (float)(*sum * (1.0 / (double)WN));
  float den = mean + QEPS;
  int n16 = WN / 16;
  int stride = gridDim.x * blockDim.x;
  for (int i = blockIdx.x * blockDim.x + threadIdx.x; i < n16; i += stride) {
    float4 v0 = w[i * 4 + 0], v1 = w[i * 4 + 1], v2 = w[i * 4 + 2], v3 = w[i * 4 + 3];
    int4 o;
    o.x = pack4div(v0, 1.f, den, -1.f, 1.f);
    o.y = pack4div(v1, 1.f, den, -1.f, 1.f);
    o.z = pack4div(v2, 1.f, den, -1.f, 1.f);
    o.w = pack4div(v3, 1.f, den, -1.f, 1.f);
    wq[i] = o;
  }
}

// -------- combine: relu^2*up, per-row gamma, int8 quant (one block per row) --
__global__ __launch_bounds__(256) void combine_kernel(
    const int* __restrict__ gate, const int* __restrict__ up,
    const float* __restrict__ scale_x, const double* __restrict__ sums,
    const float* __restrict__ sg, const float* __restrict__ su,
    float* __restrict__ gammaF, char* __restrict__ hq) {
  int row = blockIdx.x, t = threadIdx.x;
  float gm = (float)(sums[0] * (1.0 / (double)WN)) * sg[0];
  float um = (float)(sums[1] * (1.0 / (double)WN)) * su[0];
  float sx = scale_x[row];
  float sxg = sx * gm, sxu = sx * um;
  const int4* g4 = (const int4*)(gate + (size_t)row * ID);
  const int4* u4 = (const int4*)(up + (size_t)row * ID);
  float hv[11][4];
  float m = 0.f;
#pragma unroll
  for (int k = 0; k < 11; ++k) {
    int c = t + k * 256;
    if (c < ID / 4) {
      int4 gi = g4[c], ui = u4[c];
      float rg;
      rg = fmaxf((float)gi.x * sxg, 0.f); hv[k][0] = ((float)ui.x * sxu) * (rg * rg);
      rg = fmaxf((float)gi.y * sxg, 0.f); hv[k][1] = ((float)ui.y * sxu) * (rg * rg);
      rg = fmaxf((float)gi.z * sxg, 0.f); hv[k][2] = ((float)ui.z * sxu) * (rg * rg);
      rg = fmaxf((float)gi.w * sxg, 0.f); hv[k][3] = ((float)ui.w * sxu) * (rg * rg);
#pragma unroll
      for (int e = 0; e < 4; ++e) m = fmaxf(m, fabsf(hv[k][e]));
    }
  }
#pragma unroll
  for (int off = 32; off > 0; off >>= 1) m = fmaxf(m, __shfl_xor(m, off));
  __shared__ float red[4];
  if ((t & 63) == 0) red[t >> 6] = m;
  __syncthreads();
  float gamma = fmaxf(fmaxf(red[0], red[1]), fmaxf(red[2], red[3]));
  if (t == 0) gammaF[row] = gamma;
  float den = gamma + QEPS;
  int* hr = (int*)(hq + (size_t)row * ID);
#pragma unroll
  for (int k = 0; k < 11; ++k) {
    int c = t + k * 256;
    if (c < ID / 4) {
      float4 hvv = make_float4(hv[k][0], hv[k][1], hv[k][2], hv[k][3]);
      hr[c] = pack4div(hvv, 127.f, den, -128.f, 127.f);
    }
  }
}

extern "C" void kernel_launch(void* const* d_in, const int* in_sizes, int n_in,
                              void* d_out, int out_size, void* d_ws, size_t ws_size,
                              hipStream_t stream) {
  (void)in_sizes; (void)n_in; (void)out_size; (void)ws_size;
  const float* x = (const float*)d_in[0];
  const float* w_gate = (const float*)d_in[1];
  const float* w_up = (const float*)d_in[2];
  const float* w_down = (const float*)d_in[3];
  const float* s_gate = (const float*)d_in[4];
  const float* s_up = (const float*)d_in[5];
  const float* s_down = (const float*)d_in[6];
  float* out = (float*)d_out;

  // ws layout (bytes):
  char* p = (char*)d_ws;
  double* sums = (double*)p;                        // 3 doubles
  float* gammaF = (float*)(p + 256);                // 4096 f32
  float* scale_x = (float*)(p + 256 + 16384);       // 4096 f32 -> head ends 33024
  char* xq = p + 33024;                             // 16,777,216
  char* wgq = xq + 16777216UL;                      // 45,088,768 each
  char* wuq = wgq + (size_t)WN;
  char* wdq = wuq + (size_t)WN;
  int* gate_i = (int*)(wdq + (size_t)WN);           // 180,355,072
  int* up_i = (int*)((char*)gate_i + 180355072UL);  // 180,355,072
  char* hq = (char*)up_i + 180355072UL;             // 45,088,768  (~559 MB total)

  (void)hipMemsetAsync(p, 0, 256, stream);  // sums

  abssum_kernel<<<2048, 256, 0, stream>>>((const float4*)w_gate, WN / 4, sums + 0);
  abssum_kernel<<<2048, 256, 0, stream>>>((const float4*)w_up, WN / 4, sums + 1);
  abssum_kernel<<<2048, 256, 0, stream>>>((const float4*)w_down, WN / 4, sums + 2);

  quantx_kernel<<<MD, 256, 0, stream>>>(x, xq, scale_x);
  quantw_kernel<<<2048, 256, 0, stream>>>((const float4*)w_gate, (int4*)wgq, sums + 0);
  quantw_kernel<<<2048, 256, 0, stream>>>((const float4*)w_up, (int4*)wuq, sums + 1);
  quantw_kernel<<<2048, 256, 0, stream>>>((const float4*)w_down, (int4*)wdq, sums + 2);

  // gate/up: M=4096 (16 bm) x N=11008 (43 bn) -> 688 blocks (= 8*86, XCD-bijective)
  gemm_raw_kernel<<<688, 512, 0, stream>>>(xq, wgq, gate_i, HD, HD / 128, 43, ID);
  gemm_raw_kernel<<<688, 512, 0, stream>>>(xq, wuq, up_i, HD, HD / 128, 43, ID);

  combine_kernel<<<MD, 256, 0, stream>>>(gate_i, up_i, scale_x, sums, s_gate, s_up, gammaF, hq);

  // down: M=4096 x N=4096 -> 256 blocks (= 8*32), K=11008 (86 tiles)
  gemm_down_kernel<<<256, 512, 0, stream>>>(hq, wdq, out, gammaF, sums, s_down);
}

// Round 5
// 869.131 us; speedup vs baseline: 2.7207x; 1.3216x over previous
//
#include <hip/hip_runtime.h>
#include <stdint.h>

// BitNet MLP, int8-MFMA, BK=64 4-deep counted-vmcnt pipelined GEMM.
// gate|up fused (B = [wgq;wuq] 22016x4096) -> C i16 ; combine: relu^2*up,
// per-row gamma, int8 quant ; down = i8 GEMM fused scales -> f32 out.
// All integer dot products exact; only fp32 scale factors round.

typedef int i32x4 __attribute__((ext_vector_type(4)));
typedef short s16x8 __attribute__((ext_vector_type(8)));

#define HD 4096
#define ID 11008
#define MD 4096          // B*S tokens
#define WN 45088768      // 11008*4096 per weight
#define N1 22016         // gate|up fused output width
#define QEPS 1e-5f
#define SQRT7 2.6457513110645907f

#define MFMA_I8(a, b, c) __builtin_amdgcn_mfma_i32_16x16x64_i8(a, b, c, 0, 0, 0)

__device__ __forceinline__ void gload_lds16(const char* g, char* l) {
  __builtin_amdgcn_global_load_lds((const __attribute__((address_space(1))) void*)g,
                                   (__attribute__((address_space(3))) void*)l, 16, 0, 0);
}

// ---- stage a 256row x 64B tile (16KB) with 512 threads, swizzled image -----
// Desired LDS image: lds[row][slot16] = global[row][slot16 ^ (row&3)].
// gload_lds dest is linear (thread t covers byte t*16): row=t>>2, slot=t&3,
// so source slot = (t&3) ^ ((t>>2)&3). Two sweeps of 128 rows.
__device__ __forceinline__ void stage64(const char* __restrict__ g, int ldk,
                                        char* lds, int w, int l) {
  int t = w * 64 + l;
  int r = t >> 2, sl = (t & 3) ^ (r & 3);
  const char* gp = g + (size_t)r * ldk + (sl << 4);
  char* lp = lds + w * 1024;
#pragma unroll
  for (int i = 0; i < 2; ++i) {
    gload_lds16(gp, lp);
    gp += (size_t)128 * ldk;
    lp += 8192;
  }
}

// ---- 256x256 x K core: 4-deep circular buffer, prefetch dist 3 -------------
// Per iter: wait own tile (vmcnt(8) -> 2 tiles still in flight), barrier,
// issue prefetch t+3, ds_read 12 frags, 32 MFMA. Never drains to 0 mid-loop.
__device__ __forceinline__ void gemm_core(const char* __restrict__ ga,
                                          const char* __restrict__ gb,
                                          int ldk, int nt, char* lds,
                                          i32x4 (&acc)[8][4], int w, int l) {
  const int wr = (w >> 2) * 128, wc = (w & 3) * 64;
  const int lr = l & 15;
  const int sw4 = ((l >> 4) ^ (lr & 3)) << 4;  // k-quad ^ row&3, *16B
  // prologue: tiles 0,1,2
#pragma unroll
  for (int pt = 0; pt < 3; ++pt) {
    stage64(ga + (size_t)pt * 64, ldk, lds + pt * 32768, w, l);
    stage64(gb + (size_t)pt * 64, ldk, lds + pt * 32768 + 16384, w, l);
  }
  for (int t = 0; t < nt; ++t) {
    if (t + 2 < nt)      asm volatile("s_waitcnt vmcnt(8)" ::: "memory");
    else if (t + 1 < nt) asm volatile("s_waitcnt vmcnt(4)" ::: "memory");
    else                 asm volatile("s_waitcnt vmcnt(0)" ::: "memory");
    __builtin_amdgcn_s_barrier();
    if (t + 3 < nt) {  // prefetch into slot last read at iter t-1 (safe: barrier above)
      char* buf = lds + ((t + 3) & 3) * 32768;
      stage64(ga + (size_t)(t + 3) * 64, ldk, buf, w, l);
      stage64(gb + (size_t)(t + 3) * 64, ldk, buf + 16384, w, l);
    }
    const char* Ab = lds + (t & 3) * 32768;
    const char* Bb = Ab + 16384;
    i32x4 af[8], bf[4];
#pragma unroll
    for (int mi = 0; mi < 8; ++mi)
      af[mi] = *(const i32x4*)(Ab + (wr + mi * 16 + lr) * 64 + sw4);
#pragma unroll
    for (int ni = 0; ni < 4; ++ni)
      bf[ni] = *(const i32x4*)(Bb + (wc + ni * 16 + lr) * 64 + sw4);
    __builtin_amdgcn_s_setprio(1);
#pragma unroll
    for (int ni = 0; ni < 4; ++ni)
#pragma unroll
      for (int mi = 0; mi < 8; ++mi)
        acc[mi][ni] = MFMA_I8(af[mi], bf[ni], acc[mi][ni]);
    __builtin_amdgcn_s_setprio(0);
  }
}

// ---------------- GEMM1: xq x [wgq;wuq] -> C i16 ----------------------------
__global__ __launch_bounds__(512, 2) void gemm1_kernel(
    const char* __restrict__ A, const char* __restrict__ B, short* __restrict__ C) {
  __shared__ __align__(16) char lds[131072];
  int t = threadIdx.x, w = t >> 6, l = t & 63;
  // bn-major XCD mapping: on-XCD neighbors share B panels (1376 = 8*172)
  int wgid = ((int)blockIdx.x & 7) * 172 + ((int)blockIdx.x >> 3);
  int bm = wgid & 15, bn = wgid >> 4;  // bm in [0,16), bn in [0,86)
  i32x4 acc[8][4] = {};
  gemm_core(A + (size_t)bm * 256 * HD, B + (size_t)bn * 256 * HD, HD, HD / 64,
            lds, acc, w, l);
  int wr = (w >> 2) * 128, wc = (w & 3) * 64, lr = l & 15, lj = (l >> 4) * 4;
#pragma unroll
  for (int mi = 0; mi < 8; ++mi) {
    int row = bm * 256 + wr + mi * 16 + lj;
#pragma unroll
    for (int ni = 0; ni < 4; ++ni) {
      int col = bn * 256 + wc + ni * 16 + lr;
#pragma unroll
      for (int j = 0; j < 4; ++j) {
        int v = acc[mi][ni][j];
        v = v < -32768 ? -32768 : (v > 32767 ? 32767 : v);  // never triggers (|acc|<~2k)
        C[(size_t)(row + j) * N1 + col] = (short)v;
      }
    }
  }
}

// ---------------- GEMM2: hq x wdq, fused scales -> f32 ----------------------
__global__ __launch_bounds__(512, 2) void gemm_down_kernel(
    const char* __restrict__ A, const char* __restrict__ B, float* __restrict__ out,
    const float* __restrict__ gammaF, const double* __restrict__ sums,
    const float* __restrict__ sd) {
  __shared__ __align__(16) char lds[131072];
  int t = threadIdx.x, w = t >> 6, l = t & 63;
  int wgid = ((int)blockIdx.x & 7) * 32 + ((int)blockIdx.x >> 3);  // 256 = 8*32
  int bm = wgid & 15, bn = wgid >> 4;
  i32x4 acc[8][4] = {};
  gemm_core(A + (size_t)bm * 256 * ID, B + (size_t)bn * 256 * ID, ID, ID / 64,
            lds, acc, w, l);
  float wdm = (float)(sums[2] * (1.0 / (double)WN)) * sd[0] * (1.f / 127.f);
  int wr = (w >> 2) * 128, wc = (w & 3) * 64, lr = l & 15, lj = (l >> 4) * 4;
#pragma unroll
  for (int mi = 0; mi < 8; ++mi) {
    int row = bm * 256 + wr + mi * 16 + lj;
    float sa[4];
#pragma unroll
    for (int j = 0; j < 4; ++j) sa[j] = gammaF[row + j] * wdm;
#pragma unroll
    for (int ni = 0; ni < 4; ++ni) {
      int col = bn * 256 + wc + ni * 16 + lr;
#pragma unroll
      for (int j = 0; j < 4; ++j)
        out[(size_t)(row + j) * HD + col] = (float)acc[mi][ni][j] * sa[j];
    }
  }
}

// ---------------- helpers ----------------------------------------------------
__device__ __forceinline__ int pack4div(float4 v, float mul, float den, float lo, float hi) {
  int a = (int)fminf(fmaxf(rintf((v.x * mul) / den), lo), hi);
  int b = (int)fminf(fmaxf(rintf((v.y * mul) / den), lo), hi);
  int c = (int)fminf(fmaxf(rintf((v.z * mul) / den), lo), hi);
  int d = (int)fminf(fmaxf(rintf((v.w * mul) / den), lo), hi);
  return (a & 255) | ((b & 255) << 8) | ((c & 255) << 16) | ((d & 255) << 24);
}

// ---------------- absmean reductions (double atomics) -----------------------
__global__ __launch_bounds__(256) void abssum_kernel(const float4* __restrict__ w,
                                                     int n4, double* __restrict__ out) {
  float s = 0.f;
  int stride = gridDim.x * blockDim.x;
  for (int i = blockIdx.x * blockDim.x + threadIdx.x; i < n4; i += stride) {
    float4 v = w[i];
    s += fabsf(v.x) + fabsf(v.y) + fabsf(v.z) + fabsf(v.w);
  }
#pragma unroll
  for (int off = 32; off > 0; off >>= 1) s += __shfl_down(s, off);
  __shared__ float red[4];
  int l = threadIdx.x & 63, wv = threadIdx.x >> 6;
  if (l == 0) red[wv] = s;
  __syncthreads();
  if (threadIdx.x == 0) {
    double tt = (double)red[0] + (double)red[1] + (double)red[2] + (double)red[3];
    atomicAdd(out, tt);
  }
}

// ---------------- per-row beta + int4 quant of x -> i8 ----------------------
__global__ __launch_bounds__(256) void quantx_kernel(const float* __restrict__ x,
                                                     char* __restrict__ xq,
                                                     float* __restrict__ scale_x) {
  int row = blockIdx.x;
  const float4* xr = (const float4*)(x + (size_t)row * HD);
  int t = threadIdx.x;
  float4 v[4];
  float s = 0.f;
#pragma unroll
  for (int k = 0; k < 4; ++k) {
    v[k] = xr[t + k * 256];
    s += fabsf(v[k].x) + fabsf(v[k].y) + fabsf(v[k].z) + fabsf(v[k].w);
  }
#pragma unroll
  for (int off = 32; off > 0; off >>= 1) s += __shfl_down(s, off);
  __shared__ float red[4];
  int l = t & 63, wv = t >> 6;
  if (l == 0) red[wv] = s;
  __syncthreads();
  float beta = (red[0] + red[1] + red[2] + red[3]) * (1.f / (float)HD);
  if (t == 0) scale_x[row] = (beta * SQRT7) / SQRT7;  // ref dequant scale
  float den = beta + QEPS;
  int* qr = (int*)(xq + (size_t)row * HD);
#pragma unroll
  for (int k = 0; k < 4; ++k)
    qr[t + k * 256] = pack4div(v[k], SQRT7, den, -8.f, 7.f);
}

// ---------------- ternary quant of a weight -> i8 {-1,0,1} ------------------
__global__ __launch_bounds__(256) void quantw_kernel(const float4* __restrict__ w,
                                                     int4* __restrict__ wq,
                                                     const double* __restrict__ sum) {
  float mean = (float)(*sum * (1.0 / (double)WN));
  float den = mean + QEPS;
  int n16 = WN / 16;
  int stride = gridDim.x * blockDim.x;
  for (int i = blockIdx.x * blockDim.x + threadIdx.x; i < n16; i += stride) {
    float4 v0 = w[i * 4 + 0], v1 = w[i * 4 + 1], v2 = w[i * 4 + 2], v3 = w[i * 4 + 3];
    int4 o;
    o.x = pack4div(v0, 1.f, den, -1.f, 1.f);
    o.y = pack4div(v1, 1.f, den, -1.f, 1.f);
    o.z = pack4div(v2, 1.f, den, -1.f, 1.f);
    o.w = pack4div(v3, 1.f, den, -1.f, 1.f);
    wq[i] = o;
  }
}

// -------- combine: relu^2*up, per-row gamma, int8 quant (one block per row) --
__global__ __launch_bounds__(256) void combine_kernel(
    const short* __restrict__ C, const float* __restrict__ scale_x,
    const double* __restrict__ sums, const float* __restrict__ sg,
    const float* __restrict__ su, float* __restrict__ gammaF,
    char* __restrict__ hq) {
  int row = blockIdx.x, t = threadIdx.x;
  float gm = (float)(sums[0] * (1.0 / (double)WN)) * sg[0];
  float um = (float)(sums[1] * (1.0 / (double)WN)) * su[0];
  float sx = scale_x[row];
  float sxg = sx * gm, sxu = sx * um;
  const s16x8* g8 = (const s16x8*)(C + (size_t)row * N1);
  const s16x8* u8 = (const s16x8*)(C + (size_t)row * N1 + ID);
  float hv[6][8];
  float m = 0.f;
#pragma unroll
  for (int k = 0; k < 6; ++k) {
    int c = t + k * 256;
    if (c < ID / 8) {
      s16x8 gi = g8[c], ui = u8[c];
#pragma unroll
      for (int e = 0; e < 8; ++e) {
        float rg = fmaxf((float)gi[e] * sxg, 0.f);
        hv[k][e] = ((float)ui[e] * sxu) * (rg * rg);
        m = fmaxf(m, fabsf(hv[k][e]));
      }
    }
  }
#pragma unroll
  for (int off = 32; off > 0; off >>= 1) m = fmaxf(m, __shfl_xor(m, off));
  __shared__ float red[4];
  if ((t & 63) == 0) red[t >> 6] = m;
  __syncthreads();
  float gamma = fmaxf(fmaxf(red[0], red[1]), fmaxf(red[2], red[3]));
  if (t == 0) gammaF[row] = gamma;
  float den = gamma + QEPS;
  int2* hr = (int2*)(hq + (size_t)row * ID);
#pragma unroll
  for (int k = 0; k < 6; ++k) {
    int c = t + k * 256;
    if (c < ID / 8) {
      int2 o;
      o.x = pack4div(make_float4(hv[k][0], hv[k][1], hv[k][2], hv[k][3]), 127.f, den, -128.f, 127.f);
      o.y = pack4div(make_float4(hv[k][4], hv[k][5], hv[k][6], hv[k][7]), 127.f, den, -128.f, 127.f);
      hr[c] = o;
    }
  }
}

extern "C" void kernel_launch(void* const* d_in, const int* in_sizes, int n_in,
                              void* d_out, int out_size, void* d_ws, size_t ws_size,
                              hipStream_t stream) {
  (void)in_sizes; (void)n_in; (void)out_size; (void)ws_size;
  const float* x = (const float*)d_in[0];
  const float* w_gate = (const float*)d_in[1];
  const float* w_up = (const float*)d_in[2];
  const float* w_down = (const float*)d_in[3];
  const float* s_gate = (const float*)d_in[4];
  const float* s_up = (const float*)d_in[5];
  const float* s_down = (const float*)d_in[6];
  float* out = (float*)d_out;

  // ws layout (bytes):
  char* p = (char*)d_ws;
  double* sums = (double*)p;                        // 3 doubles
  float* gammaF = (float*)(p + 256);                // 4096 f32
  float* scale_x = (float*)(p + 256 + 16384);       // 4096 f32 -> head ends 33024
  char* xq = p + 33024;                             // 16,777,216
  char* wgq = xq + 16777216UL;                      // 45,088,768 (wuq contiguous after!)
  char* wuq = wgq + (size_t)WN;                     // => [wgq;wuq] = 22016 x 4096 i8
  char* wdq = wuq + (size_t)WN;
  short* C16 = (short*)(wdq + (size_t)WN);          // 180,355,072 (4096 x 22016 i16)
  char* hq = (char*)C16 + 180355072UL;              // 45,088,768  (~378 MB total)

  (void)hipMemsetAsync(p, 0, 256, stream);  // sums

  // interleave per weight so quantw's re-read hits L3 (each weight f32 = 180MB)
  abssum_kernel<<<2048, 256, 0, stream>>>((const float4*)w_gate, WN / 4, sums + 0);
  quantw_kernel<<<2048, 256, 0, stream>>>((const float4*)w_gate, (int4*)wgq, sums + 0);
  abssum_kernel<<<2048, 256, 0, stream>>>((const float4*)w_up, WN / 4, sums + 1);
  quantw_kernel<<<2048, 256, 0, stream>>>((const float4*)w_up, (int4*)wuq, sums + 1);
  abssum_kernel<<<2048, 256, 0, stream>>>((const float4*)w_down, WN / 4, sums + 2);
  quantw_kernel<<<2048, 256, 0, stream>>>((const float4*)w_down, (int4*)wdq, sums + 2);

  quantx_kernel<<<MD, 256, 0, stream>>>(x, xq, scale_x);

  // fused gate|up: M=4096 (16 bm) x N=22016 (86 bn) -> 1376 blocks (= 8*172)
  gemm1_kernel<<<1376, 512, 0, stream>>>(xq, wgq, C16);

  combine_kernel<<<MD, 256, 0, stream>>>(C16, scale_x, sums, s_gate, s_up, gammaF, hq);

  // down: M=4096 x N=4096 -> 256 blocks (= 8*32), K=11008 (172 BK=64 tiles)
  gemm_down_kernel<<<256, 512, 0, stream>>>(hq, wdq, out, gammaF, sums, s_down);
}